// Round 5
// baseline (351.416 us; speedup 1.0000x reference)
//
#include <hip/hip_runtime.h>
#include <stdint.h>

typedef float floatx4 __attribute__((ext_vector_type(4)));
typedef int intx8 __attribute__((ext_vector_type(8)));

#define FP8_MAX 448.0f
#define BM 128
#define BN 128
#define BK 128
#define GX 2048   // blocks covering x in amax
#define GW 256    // blocks covering w

// ---------------------------------------------------------------- amax partials
__global__ void amax_partial(const float* __restrict__ x, long n4x,
                             const float* __restrict__ w, long n4w,
                             float* __restrict__ part) {
    const float4* p4; long n4, i0, stride;
    if (blockIdx.x < GX) {
        p4 = (const float4*)x; n4 = n4x;
        i0 = (long)blockIdx.x * blockDim.x + threadIdx.x;
        stride = (long)GX * blockDim.x;
    } else {
        p4 = (const float4*)w; n4 = n4w;
        i0 = (long)(blockIdx.x - GX) * blockDim.x + threadIdx.x;
        stride = (long)GW * blockDim.x;
    }
    float m = 0.f;
    for (long i = i0; i < n4; i += stride) {
        float4 v = p4[i];
        m = fmaxf(m, fmaxf(fmaxf(fabsf(v.x), fabsf(v.y)),
                           fmaxf(fabsf(v.z), fabsf(v.w))));
    }
    #pragma unroll
    for (int off = 32; off > 0; off >>= 1) m = fmaxf(m, __shfl_down(m, off, 64));
    __shared__ float red[4];
    if ((threadIdx.x & 63) == 0) red[threadIdx.x >> 6] = m;
    __syncthreads();
    if (threadIdx.x == 0)
        part[blockIdx.x] = fmaxf(fmaxf(red[0], red[1]), fmaxf(red[2], red[3]));
}

// ---------------------------------------------------------------- w-quant + publish scales
__global__ void quantw_scales(const float* __restrict__ part,
                              const float* __restrict__ w, int4* __restrict__ wq,
                              long n16w, float* __restrict__ scales) {
    const int tid = threadIdx.x;
    float mx = 0.f, mw = 0.f;
    for (int i = tid; i < GX; i += 256) mx = fmaxf(mx, part[i]);
    for (int i = GX + tid; i < GX + GW; i += 256) mw = fmaxf(mw, part[i]);
    #pragma unroll
    for (int off = 32; off > 0; off >>= 1) {
        mx = fmaxf(mx, __shfl_down(mx, off, 64));
        mw = fmaxf(mw, __shfl_down(mw, off, 64));
    }
    __shared__ float rx[4], rw[4];
    if ((tid & 63) == 0) { rx[tid >> 6] = mx; rw[tid >> 6] = mw; }
    __syncthreads();
    const float ax = fmaxf(fmaxf(rx[0], rx[1]), fmaxf(rx[2], rx[3]));
    const float aw = fmaxf(fmaxf(rw[0], rw[1]), fmaxf(rw[2], rw[3]));
    const float sx = FP8_MAX / fmaxf(ax, 1e-12f);
    const float sw = FP8_MAX / fmaxf(aw, 1e-12f);
    if (blockIdx.x == 0 && tid == 0) {
        scales[0] = sx; scales[1] = sw; scales[2] = 1.0f / (sx * sw);
    }
    const float4* p4 = (const float4*)w;
    const long i = (long)blockIdx.x * 256 + tid;
    if (i < n16w) {
        float4 v0 = p4[i * 4 + 0];
        float4 v1 = p4[i * 4 + 1];
        float4 v2 = p4[i * 4 + 2];
        float4 v3 = p4[i * 4 + 3];
        int w0 = 0, w1 = 0, w2 = 0, w3 = 0;
        w0 = __builtin_amdgcn_cvt_pk_fp8_f32(v0.x * sw, v0.y * sw, w0, false);
        w0 = __builtin_amdgcn_cvt_pk_fp8_f32(v0.z * sw, v0.w * sw, w0, true);
        w1 = __builtin_amdgcn_cvt_pk_fp8_f32(v1.x * sw, v1.y * sw, w1, false);
        w1 = __builtin_amdgcn_cvt_pk_fp8_f32(v1.z * sw, v1.w * sw, w1, true);
        w2 = __builtin_amdgcn_cvt_pk_fp8_f32(v2.x * sw, v2.y * sw, w2, false);
        w2 = __builtin_amdgcn_cvt_pk_fp8_f32(v2.z * sw, v2.w * sw, w2, true);
        w3 = __builtin_amdgcn_cvt_pk_fp8_f32(v3.x * sw, v3.y * sw, w3, false);
        w3 = __builtin_amdgcn_cvt_pk_fp8_f32(v3.z * sw, v3.w * sw, w3, true);
        wq[i] = make_int4(w0, w1, w2, w3);
    }
}

// ---------------------------------------------------------------- fused quant-A + GEMM, 2-deep pipeline
// A: x [M][K] f32 -> fp8 in-register (scale sx) -> swizzled ds_write into tA.
// B: wq [N][K] fp8 via global_load_lds, double-buffered tB0/tB1, issued 1 tile ahead.
// A prefetch is 2 tiles deep (preA/preB ping-pong, statically indexed via 2x unroll),
// so issue->use distance ~2 iterations (>900cy HBM latency).
// Steady-state outstanding vmem at the pre-barrier wait (oldest first):
//   [B(t) 4][A(t+1) 16][B(t+1) 4][A(t+2) 16] = 40  ->  vmcnt(36) retires exactly B(t),
// leaving both A streams + B(t+1) in flight across both barriers. cvt's wait on A(t)
// is compiler-inserted (tracked loads) and is a no-op at distance 2.
__global__ __launch_bounds__(256) void gemm_fp8mx(
    const float* __restrict__ xf, const unsigned char* __restrict__ Bq,
    const float* __restrict__ bias, const float* __restrict__ scales,
    float* __restrict__ out, int M, int N, int K) {
    __shared__ __align__(16) unsigned char tA[BM * BK];
    __shared__ __align__(16) unsigned char tB0[BN * BK];
    __shared__ __align__(16) unsigned char tB1[BN * BK];

    const int tid = threadIdx.x;
    const int lane = tid & 63;
    const int wave = tid >> 6;
    const int waveM = (wave & 1) * 64;
    const int waveN = (wave >> 1) * 64;

    // ---- XCD-aware bijective swizzle of the flat block id ----
    const int nbx = gridDim.x;                       // N/BN (= 8)
    const int nwg = nbx * gridDim.y;                 // 2048
    int bx = blockIdx.x, by = blockIdx.y;
    if (nbx == 8 && (nwg & 7) == 0) {
        const int f   = by * 8 + bx;
        const int per = nwg >> 3;                    // blocks per XCD
        const int sw  = (f & 7) * per + (f >> 3);    // bijective since nwg%8==0
        bx = sw & 7;
        by = sw >> 3;
    }
    const long m0 = (long)by * BM;
    const int n0 = bx * BN;

    const int srow = lane >> 3;   // 0..7 row within staging call
    const int sphys = lane & 7;   // physical 16B chunk

    const float sx = scales[0];
    const float inv = scales[2];

    floatx4 acc[4][4];
    #pragma unroll
    for (int i = 0; i < 4; ++i)
        #pragma unroll
        for (int j = 0; j < 4; ++j)
            acc[i][j] = (floatx4){0.f, 0.f, 0.f, 0.f};

    const int row16 = lane & 15;
    const int q2 = (lane >> 4) * 2;   // logical chunk base = 2*quad

    const float4* x4 = (const float4*)xf;
    const int K4 = K >> 2;
    const int KLAST = K - BK;         // clamp target for tail issues

    // Per-thread A coverage: row = tid>>3 (+32j), float4 col base (tid&7)*4.
    const int arow0 = tid >> 3;
    const int ac4   = (tid & 7) * 4;
    const int aphys = tid & 7;

#define ISSUE_B(kt, tBdst) do {                                                     \
    const int kb_ = (kt);                                                           \
    _Pragma("unroll")                                                               \
    for (int c = 0; c < 4; ++c) {                                                   \
        const int r_ = wave * 32 + c * 8 + srow;                                    \
        const int lc_ = (sphys ^ (r_ & 7)) * 16;                                    \
        __builtin_amdgcn_global_load_lds(                                           \
            (const __attribute__((address_space(1))) void*)(Bq + (long)(n0 + r_) * K + kb_ + lc_), \
            (__attribute__((address_space(3))) void*)&(tBdst)[r_ * BK + sphys * 16], 16, 0, 0);    \
    } } while (0)

#define ISSUE_A(kt, pre) do {                                                       \
    const int kq_ = (kt) >> 2;                                                      \
    _Pragma("unroll")                                                               \
    for (int j = 0; j < 4; ++j) {                                                   \
        const int row_ = arow0 + 32 * j;                                            \
        const float4* px_ = x4 + (m0 + row_) * (long)K4 + kq_ + ac4;                \
        pre[j * 4 + 0] = px_[0];                                                    \
        pre[j * 4 + 1] = px_[1];                                                    \
        pre[j * 4 + 2] = px_[2];                                                    \
        pre[j * 4 + 3] = px_[3];                                                    \
    } } while (0)

#define CVT_STORE(pre) do {                                                         \
    _Pragma("unroll")                                                               \
    for (int j = 0; j < 4; ++j) {                                                   \
        const float4 v0_ = pre[j * 4 + 0];                                          \
        const float4 v1_ = pre[j * 4 + 1];                                          \
        const float4 v2_ = pre[j * 4 + 2];                                          \
        const float4 v3_ = pre[j * 4 + 3];                                          \
        int w0_ = 0, w1_ = 0, w2_ = 0, w3_ = 0;                                     \
        w0_ = __builtin_amdgcn_cvt_pk_fp8_f32(v0_.x * sx, v0_.y * sx, w0_, false);  \
        w0_ = __builtin_amdgcn_cvt_pk_fp8_f32(v0_.z * sx, v0_.w * sx, w0_, true);   \
        w1_ = __builtin_amdgcn_cvt_pk_fp8_f32(v1_.x * sx, v1_.y * sx, w1_, false);  \
        w1_ = __builtin_amdgcn_cvt_pk_fp8_f32(v1_.z * sx, v1_.w * sx, w1_, true);   \
        w2_ = __builtin_amdgcn_cvt_pk_fp8_f32(v2_.x * sx, v2_.y * sx, w2_, false);  \
        w2_ = __builtin_amdgcn_cvt_pk_fp8_f32(v2_.z * sx, v2_.w * sx, w2_, true);   \
        w3_ = __builtin_amdgcn_cvt_pk_fp8_f32(v3_.x * sx, v3_.y * sx, w3_, false);  \
        w3_ = __builtin_amdgcn_cvt_pk_fp8_f32(v3_.z * sx, v3_.w * sx, w3_, true);   \
        const int row_ = arow0 + 32 * j;                                            \
        const int phys_ = aphys ^ (row_ & 7);                                       \
        *(int4*)&tA[row_ * BK + phys_ * 16] = make_int4(w0_, w1_, w2_, w3_);        \
    } } while (0)

#define FRAG_MFMA(tBcur) do {                                                       \
    intx8 af_[4], bf_[4];                                                           \
    _Pragma("unroll")                                                               \
    for (int t_ = 0; t_ < 4; ++t_) {                                                \
        const int row_ = waveM + t_ * 16 + row16;                                   \
        const int s_ = row_ & 7;                                                    \
        const int4 lo_ = *(const int4*)&tA[row_ * BK + ((q2 ^ s_)) * 16];           \
        const int4 hi_ = *(const int4*)&tA[row_ * BK + (((q2 + 1) ^ s_)) * 16];     \
        af_[t_] = (intx8){lo_.x, lo_.y, lo_.z, lo_.w, hi_.x, hi_.y, hi_.z, hi_.w};  \
    }                                                                               \
    _Pragma("unroll")                                                               \
    for (int t_ = 0; t_ < 4; ++t_) {                                                \
        const int row_ = waveN + t_ * 16 + row16;                                   \
        const int s_ = row_ & 7;                                                    \
        const int4 lo_ = *(const int4*)&(tBcur)[row_ * BK + ((q2 ^ s_)) * 16];      \
        const int4 hi_ = *(const int4*)&(tBcur)[row_ * BK + (((q2 + 1) ^ s_)) * 16];\
        bf_[t_] = (intx8){lo_.x, lo_.y, lo_.z, lo_.w, hi_.x, hi_.y, hi_.z, hi_.w};  \
    }                                                                               \
    _Pragma("unroll")                                                               \
    for (int mt_ = 0; mt_ < 4; ++mt_)                                               \
        _Pragma("unroll")                                                           \
        for (int nt_ = 0; nt_ < 4; ++nt_)                                           \
            acc[mt_][nt_] = __builtin_amdgcn_mfma_scale_f32_16x16x128_f8f6f4(       \
                af_[mt_], bf_[nt_], acc[mt_][nt_], 0, 0, 0, 127, 0, 127);           \
    } while (0)

#define BODY(t, preCur, tBnext, tBcur) do {                                         \
    const int ktB_ = ((t) + 1) * BK <= KLAST ? ((t) + 1) * BK : KLAST;              \
    const int ktA_ = ((t) + 2) * BK <= KLAST ? ((t) + 2) * BK : KLAST;              \
    ISSUE_B(ktB_, tBnext);                                                          \
    __builtin_amdgcn_sched_barrier(0);                                              \
    CVT_STORE(preCur);                                                              \
    __builtin_amdgcn_sched_barrier(0);                                              \
    ISSUE_A(ktA_, preCur);                                                          \
    asm volatile("s_waitcnt vmcnt(36) lgkmcnt(0)" ::: "memory");                    \
    __builtin_amdgcn_s_barrier();                                                   \
    __builtin_amdgcn_sched_barrier(0);                                              \
    FRAG_MFMA(tBcur);                                                               \
    __builtin_amdgcn_s_barrier();                                                   \
    __builtin_amdgcn_sched_barrier(0);                                              \
} while (0)

    // ---- prologue: B(0) -> tB0, A(0) -> preA, A(1) -> preB ----
    float4 preA[16], preB[16];
    ISSUE_B(0, tB0);
    ISSUE_A(0, preA);
    {
        const int k1 = BK <= KLAST ? BK : KLAST;
        ISSUE_A(k1, preB);
    }

    const int NT = K / BK;            // 8 (K=1024); loop requires NT even
    for (int t = 0; t < NT; t += 2) {
        BODY(t,     preA, tB1, tB0);
        BODY(t + 1, preB, tB0, tB1);
    }

#undef BODY
#undef FRAG_MFMA
#undef CVT_STORE
#undef ISSUE_A
#undef ISSUE_B

    const int col = lane & 15;          // C/D: col = lane&15
    const int rbase4 = (lane >> 4) * 4; // row = quad*4 + reg
    #pragma unroll
    for (int nt = 0; nt < 4; ++nt) {
        const int gn = n0 + waveN + nt * 16 + col;
        const float bv = bias[gn];
        #pragma unroll
        for (int mt = 0; mt < 4; ++mt) {
            const long gm = m0 + waveM + mt * 16 + rbase4;
            float* po = out + gm * (long)N + gn;
            #pragma unroll
            for (int r = 0; r < 4; ++r)
                po[(long)r * N] = acc[mt][nt][r] * inv + bv;
        }
    }
}

// ---------------------------------------------------------------- launch
extern "C" void kernel_launch(void* const* d_in, const int* in_sizes, int n_in,
                              void* d_out, int out_size, void* d_ws, size_t ws_size,
                              hipStream_t stream) {
    const float* x = (const float*)d_in[0];
    const float* w = (const float*)d_in[1];
    const float* bias = (const float*)d_in[2];
    float* out = (float*)d_out;

    const long nx = in_sizes[0];   // M*K
    const long nw = in_sizes[1];   // N*K
    const int N = in_sizes[2];     // 1024
    const long K = nw / N;         // 1024
    const long M = nx / K;         // 32768

    unsigned char* ws = (unsigned char*)d_ws;
    unsigned char* wq = ws;                         // nw bytes fp8
    float* part = (float*)(ws + nw);                // GX+GW partial maxima
    float* scales = (float*)(ws + nw + 16384);      // {sx, sw, inv}

    amax_partial<<<GX + GW, 256, 0, stream>>>(x, nx / 4, w, nw / 4, part);
    quantw_scales<<<GW, 256, 0, stream>>>(part, w, (int4*)wq, nw / 16, scales);

    dim3 grid(N / BN, (int)(M / BM));
    gemm_fp8mx<<<grid, 256, 0, stream>>>(x, wq, bias, scales, out,
                                         (int)M, N, (int)K);
}

// Round 6
// 292.430 us; speedup vs baseline: 1.2017x; 1.2017x over previous
//
#include <hip/hip_runtime.h>
#include <stdint.h>

typedef float floatx4 __attribute__((ext_vector_type(4)));
typedef int intx8 __attribute__((ext_vector_type(8)));

#define FP8_MAX 448.0f
#define BM 128
#define BN 128
#define BK 128
#define GX 2048   // blocks covering x in amax/quant
#define GW 256    // blocks covering w

// ---------------------------------------------------------------- amax partials
__global__ void amax_partial(const float* __restrict__ x, long n4x,
                             const float* __restrict__ w, long n4w,
                             float* __restrict__ part) {
    const float4* p4; long n4, i0, stride;
    if (blockIdx.x < GX) {
        p4 = (const float4*)x; n4 = n4x;
        i0 = (long)blockIdx.x * blockDim.x + threadIdx.x;
        stride = (long)GX * blockDim.x;
    } else {
        p4 = (const float4*)w; n4 = n4w;
        i0 = (long)(blockIdx.x - GX) * blockDim.x + threadIdx.x;
        stride = (long)GW * blockDim.x;
    }
    float m = 0.f;
    for (long i = i0; i < n4; i += stride) {
        float4 v = p4[i];
        m = fmaxf(m, fmaxf(fmaxf(fabsf(v.x), fabsf(v.y)),
                           fmaxf(fabsf(v.z), fabsf(v.w))));
    }
    #pragma unroll
    for (int off = 32; off > 0; off >>= 1) m = fmaxf(m, __shfl_down(m, off, 64));
    __shared__ float red[4];
    if ((threadIdx.x & 63) == 0) red[threadIdx.x >> 6] = m;
    __syncthreads();
    if (threadIdx.x == 0)
        part[blockIdx.x] = fmaxf(fmaxf(red[0], red[1]), fmaxf(red[2], red[3]));
}

// ---------------------------------------------------------------- quant x+w, publish scales
// Every block redundantly reduces the 9 KiB partial array (trivial, L2-hot),
// so the finalize dispatch is absorbed. Block 0 publishes {sx, sw, inv}.
// Blocks < GX quantize x (grid-stride); blocks >= GX quantize w (one shot).
__global__ void quant_all(const float* __restrict__ part,
                          const float* __restrict__ x, int4* __restrict__ xq, long n16x,
                          const float* __restrict__ w, int4* __restrict__ wq, long n16w,
                          float* __restrict__ scales) {
    const int tid = threadIdx.x;
    float mx = 0.f, mw = 0.f;
    for (int i = tid; i < GX; i += 256) mx = fmaxf(mx, part[i]);
    for (int i = GX + tid; i < GX + GW; i += 256) mw = fmaxf(mw, part[i]);
    #pragma unroll
    for (int off = 32; off > 0; off >>= 1) {
        mx = fmaxf(mx, __shfl_down(mx, off, 64));
        mw = fmaxf(mw, __shfl_down(mw, off, 64));
    }
    __shared__ float rx[4], rw[4];
    if ((tid & 63) == 0) { rx[tid >> 6] = mx; rw[tid >> 6] = mw; }
    __syncthreads();
    const float ax = fmaxf(fmaxf(rx[0], rx[1]), fmaxf(rx[2], rx[3]));
    const float aw = fmaxf(fmaxf(rw[0], rw[1]), fmaxf(rw[2], rw[3]));
    const float sx = FP8_MAX / fmaxf(ax, 1e-12f);
    const float sw = FP8_MAX / fmaxf(aw, 1e-12f);
    if (blockIdx.x == 0 && tid == 0) {
        scales[0] = sx; scales[1] = sw; scales[2] = 1.0f / (sx * sw);
    }

    const float4* p4; int4* o; long n16, i0, stride; float s;
    if (blockIdx.x < GX) {
        p4 = (const float4*)x; o = xq; n16 = n16x; s = sx;
        i0 = (long)blockIdx.x * 256 + tid;
        stride = (long)GX * 256;
    } else {
        p4 = (const float4*)w; o = wq; n16 = n16w; s = sw;
        i0 = (long)(blockIdx.x - GX) * 256 + tid;
        stride = (long)GW * 256;
    }
    for (long i = i0; i < n16; i += stride) {
        float4 v0 = p4[i * 4 + 0];
        float4 v1 = p4[i * 4 + 1];
        float4 v2 = p4[i * 4 + 2];
        float4 v3 = p4[i * 4 + 3];
        int w0 = 0, w1 = 0, w2 = 0, w3 = 0;
        w0 = __builtin_amdgcn_cvt_pk_fp8_f32(v0.x * s, v0.y * s, w0, false);
        w0 = __builtin_amdgcn_cvt_pk_fp8_f32(v0.z * s, v0.w * s, w0, true);
        w1 = __builtin_amdgcn_cvt_pk_fp8_f32(v1.x * s, v1.y * s, w1, false);
        w1 = __builtin_amdgcn_cvt_pk_fp8_f32(v1.z * s, v1.w * s, w1, true);
        w2 = __builtin_amdgcn_cvt_pk_fp8_f32(v2.x * s, v2.y * s, w2, false);
        w2 = __builtin_amdgcn_cvt_pk_fp8_f32(v2.z * s, v2.w * s, w2, true);
        w3 = __builtin_amdgcn_cvt_pk_fp8_f32(v3.x * s, v3.y * s, w3, false);
        w3 = __builtin_amdgcn_cvt_pk_fp8_f32(v3.z * s, v3.w * s, w3, true);
        o[i] = make_int4(w0, w1, w2, w3);
    }
}

// ---------------------------------------------------------------- GEMM, LDS double-buffered
// A: xq [M][K] fp8, B: wq [N][K] fp8, both staged by global_load_lds (16B).
// LDS: 2 buffers per operand (64 KiB total). Pipeline (T3/T4 minimum 2-phase):
//   prologue: STAGE(tile 0 -> buf0)
//   iter t:   STAGE(tile t+1 -> buf[t+1&1])   (last iter: redundant re-stage, keeps count)
//             s_waitcnt vmcnt(8)    <- per-wave 8 loads/tile; retires EXACTLY tile t,
//                                      tile t+1's 8 loads stay in flight across barriers
//             s_barrier; FRAG+16 MFMA on buf[t&1]; s_barrier
// No vmcnt(0) drain in the loop: tile t+1's HBM/L2 latency hides under tile t's
// ds_read+MFMA and the other resident block's work. Zero VGPR cost (vs r5's failure).
// Epilogue uses NON-TEMPORAL stores: out is never re-read; stop it evicting xq/wq
// from L2/L3 (round-1 FETCH_SIZE 84 MB vs 33 MB working set = eviction re-fetch).
__global__ __launch_bounds__(256) void gemm_fp8mx(
    const unsigned char* __restrict__ Aq, const unsigned char* __restrict__ Bq,
    const float* __restrict__ bias, const float* __restrict__ scales,
    float* __restrict__ out, int M, int N, int K) {
    __shared__ __align__(16) unsigned char tA[2][BM * BK];
    __shared__ __align__(16) unsigned char tB[2][BN * BK];

    const int tid = threadIdx.x;
    const int lane = tid & 63;
    const int wave = tid >> 6;
    const int waveM = (wave & 1) * 64;
    const int waveN = (wave >> 1) * 64;

    // ---- XCD-aware bijective swizzle of the flat block id ----
    const int nbx = gridDim.x;                       // N/BN (= 8)
    const int nwg = nbx * gridDim.y;                 // 2048
    int bx = blockIdx.x, by = blockIdx.y;
    if (nbx == 8 && (nwg & 7) == 0) {
        const int f   = by * 8 + bx;
        const int per = nwg >> 3;                    // blocks per XCD
        const int sw  = (f & 7) * per + (f >> 3);    // bijective since nwg%8==0
        bx = sw & 7;
        by = sw >> 3;
    }
    const long m0 = (long)by * BM;
    const int n0 = bx * BN;

    const int srow = lane >> 3;   // 0..7 row within staging call
    const int sphys = lane & 7;   // physical 16B chunk

    floatx4 acc[4][4];
    #pragma unroll
    for (int i = 0; i < 4; ++i)
        #pragma unroll
        for (int j = 0; j < 4; ++j)
            acc[i][j] = (floatx4){0.f, 0.f, 0.f, 0.f};

    const int row16 = lane & 15;
    const int q2 = (lane >> 4) * 2;   // logical chunk base = 2*quad

#define STAGE(kt, b) do {                                                            \
    const int kb_ = (kt);                                                            \
    _Pragma("unroll")                                                                \
    for (int c = 0; c < 4; ++c) {                                                    \
        const int r_ = wave * 32 + c * 8 + srow;                                     \
        const int lc_ = (sphys ^ (r_ & 7)) * 16;   /* pre-swizzled source offset */  \
        __builtin_amdgcn_global_load_lds(                                            \
            (const __attribute__((address_space(1))) void*)(Aq + (m0 + r_) * (long)K + kb_ + lc_), \
            (__attribute__((address_space(3))) void*)&tA[b][r_ * BK + sphys * 16], 16, 0, 0);      \
        __builtin_amdgcn_global_load_lds(                                            \
            (const __attribute__((address_space(1))) void*)(Bq + (long)(n0 + r_) * K + kb_ + lc_), \
            (__attribute__((address_space(3))) void*)&tB[b][r_ * BK + sphys * 16], 16, 0, 0);      \
    } } while (0)

    const int NT = K / BK;            // 8
    const int KLAST = K - BK;

    // ---- prologue: tile 0 -> buffer 0 ----
    STAGE(0, 0);

    for (int t = 0; t < NT; ++t) {
        const int cur = t & 1;
        const int nxt = cur ^ 1;
        // Issue next tile (redundant re-stage of the last tile keeps the
        // per-wave outstanding-vmem count uniform at 16 -> vmcnt(8) is exact).
        const int kst = (t + 1 < NT) ? (t + 1) * BK : KLAST;
        STAGE(kst, nxt);

        // Retire exactly tile t's 8 loads (oldest in this wave's FIFO);
        // tile t+1's 8 stay in flight across both barriers.
        asm volatile("s_waitcnt vmcnt(8)" ::: "memory");
        __builtin_amdgcn_s_barrier();
        __builtin_amdgcn_sched_barrier(0);

        // ---- frags (compiler inserts counted lgkmcnt before MFMA use) ----
        intx8 af[4], bf[4];
        #pragma unroll
        for (int u = 0; u < 4; ++u) {
            const int row = waveM + u * 16 + row16;
            const int s = row & 7;
            const int4 lo = *(const int4*)&tA[cur][row * BK + ((q2 ^ s)) * 16];
            const int4 hi = *(const int4*)&tA[cur][row * BK + (((q2 + 1) ^ s)) * 16];
            af[u] = (intx8){lo.x, lo.y, lo.z, lo.w, hi.x, hi.y, hi.z, hi.w};
        }
        #pragma unroll
        for (int u = 0; u < 4; ++u) {
            const int row = waveN + u * 16 + row16;
            const int s = row & 7;
            const int4 lo = *(const int4*)&tB[cur][row * BK + ((q2 ^ s)) * 16];
            const int4 hi = *(const int4*)&tB[cur][row * BK + (((q2 + 1) ^ s)) * 16];
            bf[u] = (intx8){lo.x, lo.y, lo.z, lo.w, hi.x, hi.y, hi.z, hi.w};
        }
        #pragma unroll
        for (int mt = 0; mt < 4; ++mt)
            #pragma unroll
            for (int nt = 0; nt < 4; ++nt)
                acc[mt][nt] = __builtin_amdgcn_mfma_scale_f32_16x16x128_f8f6f4(
                    af[mt], bf[nt], acc[mt][nt], 0, 0, /*A=fp8,B=fp8*/
                    0, 127, 0, 127);                   /* unit E8M0 scales */

        // All my frag ds_reads retired (forced by MFMA operand waits); barrier
        // so no wave's next STAGE overwrites a buffer someone still reads.
        __builtin_amdgcn_s_barrier();
        __builtin_amdgcn_sched_barrier(0);
    }
#undef STAGE

    const float inv = scales[2];
    const int col = lane & 15;          // C/D: col = lane&15
    const int rbase4 = (lane >> 4) * 4; // row = quad*4 + reg
    #pragma unroll
    for (int nt = 0; nt < 4; ++nt) {
        const int gn = n0 + waveN + nt * 16 + col;
        const float bv = bias[gn];
        #pragma unroll
        for (int mt = 0; mt < 4; ++mt) {
            const long gm = m0 + waveM + mt * 16 + rbase4;
            float* po = out + gm * (long)N + gn;
            #pragma unroll
            for (int r = 0; r < 4; ++r)
                __builtin_nontemporal_store(acc[mt][nt][r] * inv + bv, po + (long)r * N);
        }
    }
}

// ---------------------------------------------------------------- launch
extern "C" void kernel_launch(void* const* d_in, const int* in_sizes, int n_in,
                              void* d_out, int out_size, void* d_ws, size_t ws_size,
                              hipStream_t stream) {
    const float* x = (const float*)d_in[0];
    const float* w = (const float*)d_in[1];
    const float* bias = (const float*)d_in[2];
    float* out = (float*)d_out;

    const long nx = in_sizes[0];   // M*K
    const long nw = in_sizes[1];   // N*K
    const int N = in_sizes[2];     // 1024
    const long K = nw / N;         // 1024
    const long M = nx / K;         // 32768

    unsigned char* ws = (unsigned char*)d_ws;
    unsigned char* xq = ws;                         // nx bytes fp8
    unsigned char* wq = ws + nx;                    // nw bytes fp8
    float* part = (float*)(ws + nx + nw);           // GX+GW partial maxima
    float* scales = (float*)(ws + nx + nw + 16384); // {sx, sw, inv}

    amax_partial<<<GX + GW, 256, 0, stream>>>(x, nx / 4, w, nw / 4, part);
    quant_all<<<GX + GW, 256, 0, stream>>>(part, x, (int4*)xq, nx / 16,
                                           w, (int4*)wq, nw / 16, scales);

    dim3 grid(N / BN, (int)(M / BM));
    gemm_fp8mx<<<grid, 256, 0, stream>>>(xq, wq, bias, scales, out,
                                         (int)M, N, (int)K);
}